// Round 1
// baseline (1584.802 us; speedup 1.0000x reference)
//
#include <hip/hip_runtime.h>

#define BB 2048
#define IMG 784
#define HWD 28
#define C1 32
#define C2 64
#define PP 169
#define PD 13
#define F3 10816
#define N3 2048
#define K3W 169
#define K4W 32
#define NOUT 10

__device__ __forceinline__ float ap2mag(float c) {
    // 2^round(log2(max(|c|,1e-38)))  (round half to even, like jnp.round)
    float a = fmaxf(fabsf(c), 1e-38f);
    return exp2f(rintf(log2f(a)));
}

// ---------------- conv1 (fp32 x, binarized weights) ----------------
// pass 0: per-channel sum of relu(conv+b); pass 1: per-channel sum of c*ap2(c)
__global__ void conv1_stats(const float* __restrict__ x, const float* __restrict__ w1,
                            const float* __restrict__ cb1, const float* __restrict__ meanIn,
                            double* __restrict__ outSum, int pass) {
    __shared__ float xs[IMG];
    __shared__ float ws[C1 * 9];
    __shared__ float red[256];
    __shared__ float ms[C1];
    int n = blockIdx.x, tid = threadIdx.x;
    for (int i = tid; i < IMG; i += 256) xs[i] = x[n * IMG + i];
    for (int i = tid; i < C1 * 9; i += 256) ws[i] = (w1[i] >= 0.f) ? 1.f : -1.f;
    if (tid < C1) ms[tid] = pass ? meanIn[tid] : 0.f;
    __syncthreads();
    int ch = tid & 31, slice = tid >> 5;
    float b = cb1[ch];
    float m = ms[ch];
    float acc = 0.f;
    for (int p = slice; p < IMG; p += 8) {
        int py = p / HWD, px = p % HWD;
        float s = 0.f;
#pragma unroll
        for (int ky = 0; ky < 3; ky++) {
            int yy = py + ky - 1;
            if (yy < 0 || yy >= HWD) continue;
#pragma unroll
            for (int kx = 0; kx < 3; kx++) {
                int xx = px + kx - 1;
                if (xx < 0 || xx >= HWD) continue;
                s += xs[yy * HWD + xx] * ws[ch * 9 + ky * 3 + kx];
            }
        }
        float v = fmaxf(s + b, 0.f);
        if (pass == 0) acc += v;
        else { float c = v - m; acc += fabsf(c) * ap2mag(c); }
    }
    red[tid] = acc;
    __syncthreads();
    if (tid < C1) {
        float t = 0.f;
        for (int sl = 0; sl < 8; sl++) t += red[sl * 32 + tid];
        atomicAdd(&outSum[tid], (double)t);
    }
}

// binarize(shift_bn(relu(conv1))) -> 32 channel bits packed per pixel
__global__ void conv1_pack(const float* __restrict__ x, const float* __restrict__ w1,
                           const float* __restrict__ cb1, const float* __restrict__ mean1,
                           const float* __restrict__ scale1, const float* __restrict__ beta1,
                           unsigned int* __restrict__ s1p) {
    __shared__ float xs[IMG];
    __shared__ float ws[C1 * 9];
    __shared__ float ms[C1], sc[C1], bt[C1], bbs[C1];
    int n = blockIdx.x, tid = threadIdx.x;
    for (int i = tid; i < IMG; i += 256) xs[i] = x[n * IMG + i];
    for (int i = tid; i < C1 * 9; i += 256) ws[i] = (w1[i] >= 0.f) ? 1.f : -1.f;
    if (tid < C1) { ms[tid] = mean1[tid]; sc[tid] = scale1[tid]; bt[tid] = beta1[tid]; bbs[tid] = cb1[tid]; }
    __syncthreads();
    for (int p = tid; p < IMG; p += 256) {
        int py = p / HWD, px = p % HWD;
        float xw[9];
#pragma unroll
        for (int ky = 0; ky < 3; ky++)
#pragma unroll
            for (int kx = 0; kx < 3; kx++) {
                int yy = py + ky - 1, xx = px + kx - 1;
                xw[ky * 3 + kx] = (yy >= 0 && yy < HWD && xx >= 0 && xx < HWD) ? xs[yy * HWD + xx] : 0.f;
            }
        unsigned int bits = 0;
        for (int oc = 0; oc < C1; oc++) {
            float s = 0.f;
#pragma unroll
            for (int k = 0; k < 9; k++) s += xw[k] * ws[oc * 9 + k];
            float v = fmaxf(s + bbs[oc], 0.f);
            float val = sc[oc] * (v - ms[oc]) + bt[oc];
            bits |= (val >= 0.f ? 1u : 0u) << oc;
        }
        s1p[n * IMG + p] = bits;
    }
}

// ---------------- conv2 weight packing ----------------
__global__ void pack_w2(const float* __restrict__ w2, unsigned int* __restrict__ w2p) {
    int t = blockIdx.x * blockDim.x + threadIdx.x;
    if (t >= C2 * 9) return;
    int oc = t / 9, k = t % 9;
    unsigned int bits = 0;
    for (int ic = 0; ic < C1; ic++)
        bits |= (w2[oc * 288 + ic * 9 + k] >= 0.f ? 1u : 0u) << ic;
    w2p[t] = bits;
}

// ---------------- fused conv2 + maxpool3s2 (pre-bias, pre-relu int) ----------------
__global__ void conv2pool(const unsigned int* __restrict__ s1p, const unsigned int* __restrict__ w2p,
                          short* __restrict__ p2i) {
    __shared__ unsigned int ss[IMG];
    __shared__ unsigned int wp[C2 * 9];
    int n = blockIdx.x, tid = threadIdx.x;
    for (int i = tid; i < IMG; i += 256) ss[i] = s1p[n * IMG + i];
    for (int i = tid; i < C2 * 9; i += 256) wp[i] = w2p[i];
    __syncthreads();
    for (int idx = tid; idx < C2 * PP; idx += 256) {
        int oc = idx / PP, pix = idx % PP;
        int py = pix / PD, px = pix % PD;
        int best = -1000000;
#pragma unroll
        for (int wy = 0; wy < 3; wy++) {
#pragma unroll
            for (int wx = 0; wx < 3; wx++) {
                int y = 2 * py + wy, xx0 = 2 * px + wx;
                int s = 0, cnt = 0;
#pragma unroll
                for (int ky = 0; ky < 3; ky++) {
                    int yy = y + ky - 1;
                    if (yy < 0 || yy >= HWD) continue;
#pragma unroll
                    for (int kx = 0; kx < 3; kx++) {
                        int xx = xx0 + kx - 1;
                        if (xx < 0 || xx >= HWD) continue;
                        s += __popc(ss[yy * HWD + xx] ^ wp[oc * 9 + ky * 3 + kx]);
                        cnt += 32;
                    }
                }
                int conv = cnt - 2 * s;
                best = max(best, conv);
            }
        }
        p2i[n * (C2 * PP) + idx] = (short)best;
    }
}

// ---------------- stats over pooled layer-2 ----------------
__global__ void p2_stats(const short* __restrict__ p2i, const float* __restrict__ cb2,
                         const float* __restrict__ meanIn, double* __restrict__ outSum, int pass) {
    __shared__ float red[256];
    int n = blockIdx.x, tid = threadIdx.x;
    int ch = tid & 63, slice = tid >> 6;
    float b = cb2[ch];
    float m = pass ? meanIn[ch] : 0.f;
    float acc = 0.f;
    const short* row = p2i + n * F3 + ch * PP;
    for (int p = slice; p < PP; p += 4) {
        float v = fmaxf((float)row[p] + b, 0.f);
        if (pass == 0) acc += v;
        else { float c = v - m; acc += fabsf(c) * ap2mag(c); }
    }
    red[tid] = acc;
    __syncthreads();
    if (tid < C2) {
        float t = 0.f;
        for (int sl = 0; sl < 4; sl++) t += red[sl * 64 + tid];
        atomicAdd(&outSum[tid], (double)t);
    }
}

// binarize layer-2 -> packed u64 rows (169 words per sample)
__global__ void p2_pack(const short* __restrict__ p2i, const float* __restrict__ cb2,
                        const float* __restrict__ mean2, const float* __restrict__ scale2,
                        const float* __restrict__ beta2, unsigned long long* __restrict__ hp3) {
    int gw = (blockIdx.x * blockDim.x + threadIdx.x) >> 6;
    int lane = threadIdx.x & 63;
    if (gw >= BB * K3W) return;
    int n = gw / K3W, j = gw % K3W;
    int f = j * 64 + lane;
    int oc = f / PP;
    float v = fmaxf((float)p2i[n * F3 + f] + cb2[oc], 0.f);
    float val = scale2[oc] * (v - mean2[oc]) + beta2[oc];
    unsigned long long mask = __ballot(val >= 0.f);
    if (lane == 0) hp3[n * K3W + j] = mask;
}

__global__ void w3_pack(const float* __restrict__ w3, unsigned long long* __restrict__ wp3) {
    int gw = (blockIdx.x * blockDim.x + threadIdx.x) >> 6;
    int lane = threadIdx.x & 63;
    if (gw >= N3 * K3W) return;
    int nn = gw / K3W, j = gw % K3W;
    float w = w3[(size_t)nn * F3 + j * 64 + lane];
    unsigned long long mask = __ballot(w >= 0.f);
    if (lane == 0) wp3[nn * K3W + j] = mask;
}

// ---------------- lin3: XNOR-popcount GEMM, 64x64 tile, 4x4 per thread ----------------
__global__ __launch_bounds__(256) void lin3_gemm(const unsigned long long* __restrict__ hp3,
                                                 const unsigned long long* __restrict__ wp3,
                                                 const float* __restrict__ b3l,
                                                 float* __restrict__ h3) {
    __shared__ unsigned long long aT[64][9];
    __shared__ unsigned long long bT[64][9];
    int tx = threadIdx.x & 15, ty = threadIdx.x >> 4;
    int m0 = blockIdx.y * 64, n0 = blockIdx.x * 64;
    int s[4][4];
#pragma unroll
    for (int i = 0; i < 4; i++)
#pragma unroll
        for (int j = 0; j < 4; j++) s[i][j] = 0;
    for (int k0 = 0; k0 < K3W; k0 += 8) {
        for (int t = threadIdx.x; t < 512; t += 256) {
            int r = t >> 3, kk = t & 7;
            int k = k0 + kk;
            aT[r][kk] = (k < K3W) ? hp3[(m0 + r) * K3W + k] : 0ULL;
            bT[r][kk] = (k < K3W) ? wp3[(n0 + r) * K3W + k] : 0ULL;
        }
        __syncthreads();
#pragma unroll
        for (int kk = 0; kk < 8; kk++) {
            unsigned long long a[4], b[4];
#pragma unroll
            for (int i = 0; i < 4; i++) a[i] = aT[ty * 4 + i][kk];
#pragma unroll
            for (int j = 0; j < 4; j++) b[j] = bT[tx * 4 + j][kk];
#pragma unroll
            for (int i = 0; i < 4; i++)
#pragma unroll
                for (int j = 0; j < 4; j++) s[i][j] += __popcll(a[i] ^ b[j]);
        }
        __syncthreads();
    }
#pragma unroll
    for (int i = 0; i < 4; i++) {
        int m = m0 + ty * 4 + i;
#pragma unroll
        for (int j = 0; j < 4; j++) {
            int nn = n0 + tx * 4 + j;
            float v = fmaxf((float)(F3 - 2 * s[i][j]) + b3l[nn], 0.f);
            h3[(size_t)m * N3 + nn] = v;
        }
    }
}

// ---------------- stats over h3 (per feature, across batch) ----------------
__global__ void h3_stats(const float* __restrict__ h3, const float* __restrict__ meanIn,
                         double* __restrict__ outSum, int pass) {
    int nn = blockIdx.x * 256 + threadIdx.x;
    int m0 = blockIdx.y * 128;
    float m = pass ? meanIn[nn] : 0.f;
    float acc = 0.f;
    for (int mm = m0; mm < m0 + 128; mm++) {
        float v = h3[(size_t)mm * N3 + nn];
        if (pass == 0) acc += v;
        else { float c = v - m; acc += fabsf(c) * ap2mag(c); }
    }
    atomicAdd(&outSum[nn], (double)acc);
}

__global__ void h3_pack(const float* __restrict__ h3, const float* __restrict__ mean3,
                        const float* __restrict__ scale3, const float* __restrict__ beta3,
                        unsigned long long* __restrict__ h4p) {
    int gw = (blockIdx.x * blockDim.x + threadIdx.x) >> 6;
    int lane = threadIdx.x & 63;
    if (gw >= BB * K4W) return;
    int m = gw / K4W, j = gw % K4W;
    int f = j * 64 + lane;
    float v = h3[(size_t)m * N3 + f];
    float val = scale3[f] * (v - mean3[f]) + beta3[f];
    unsigned long long mask = __ballot(val >= 0.f);
    if (lane == 0) h4p[m * K4W + j] = mask;
}

__global__ void w4_pack(const float* __restrict__ w4, unsigned long long* __restrict__ wp4) {
    int gw = (blockIdx.x * blockDim.x + threadIdx.x) >> 6;
    int lane = threadIdx.x & 63;
    if (gw >= NOUT * K4W) return;
    int o = gw / K4W, j = gw % K4W;
    float w = w4[o * N3 + j * 64 + lane];
    unsigned long long mask = __ballot(w >= 0.f);
    if (lane == 0) wp4[o * K4W + j] = mask;
}

__global__ void lin4_out(const unsigned long long* __restrict__ h4p,
                         const unsigned long long* __restrict__ wp4,
                         const float* __restrict__ b4, float* __restrict__ out) {
    int gw = (blockIdx.x * blockDim.x + threadIdx.x) >> 6;
    int lane = threadIdx.x & 63;
    if (gw >= BB * NOUT) return;
    int m = gw / NOUT, o = gw % NOUT;
    int c = 0;
    if (lane < K4W) c = __popcll(h4p[m * K4W + lane] ^ wp4[o * K4W + lane]);
    for (int off = 32; off; off >>= 1) c += __shfl_down(c, off);
    if (lane == 0) out[m * NOUT + o] = (float)(N3 - 2 * c) + b4[o];
}

// ---------------- small finalize kernels ----------------
__global__ void finalize_mean(const double* __restrict__ sumd, float* __restrict__ meanOut,
                              int n, double count) {
    int i = blockIdx.x * blockDim.x + threadIdx.x;
    if (i < n) meanOut[i] = (float)(sumd[i] / count);
}

__global__ void finalize_scale(const double* __restrict__ vard, const float* __restrict__ g,
                               float* __restrict__ scaleOut, int n, double count) {
    int i = blockIdx.x * blockDim.x + threadIdx.x;
    if (i >= n) return;
    float var = (float)(vard[i] / count);
    float t = var + 1e-4f;
    float inv = 1.0f / sqrtf(t);
    double p = exp2(rint(log2((double)inv)));
    float gg = g[i];
    float ap2g;
    if (gg == 0.f) ap2g = 0.f;
    else {
        double ag = fabs((double)gg);
        if (ag < 1e-38) ag = 1e-38;
        ap2g = (float)exp2(rint(log2(ag)));
        if (gg < 0.f) ap2g = -ap2g;
    }
    scaleOut[i] = ap2g * (float)p;
}

extern "C" void kernel_launch(void* const* d_in, const int* in_sizes, int n_in,
                              void* d_out, int out_size, void* d_ws, size_t ws_size,
                              hipStream_t stream) {
    const float* x   = (const float*)d_in[0];
    const float* w1  = (const float*)d_in[1];
    const float* cb1 = (const float*)d_in[2];
    const float* g1  = (const float*)d_in[3];
    const float* bt1 = (const float*)d_in[4];
    const float* w2  = (const float*)d_in[5];
    const float* cb2 = (const float*)d_in[6];
    const float* g2  = (const float*)d_in[7];
    const float* bt2 = (const float*)d_in[8];
    const float* w3  = (const float*)d_in[9];
    const float* b3l = (const float*)d_in[10];
    const float* g3  = (const float*)d_in[11];
    const float* bt3 = (const float*)d_in[12];
    const float* w4  = (const float*)d_in[13];
    const float* b4l = (const float*)d_in[14];
    float* out = (float*)d_out;

    char* base = (char*)d_ws;
    size_t off = 0;
    auto carve = [&](size_t bytes) { char* p = base + off; off = (off + bytes + 255) & ~(size_t)255; return p; };
    unsigned int* s1p       = (unsigned int*)carve((size_t)BB * IMG * 4);
    short* p2i              = (short*)carve((size_t)BB * C2 * PP * 2);
    unsigned long long* hp3 = (unsigned long long*)carve((size_t)BB * K3W * 8);
    unsigned long long* wp3 = (unsigned long long*)carve((size_t)N3 * K3W * 8);
    float* h3               = (float*)carve((size_t)BB * N3 * 4);
    unsigned long long* h4p = (unsigned long long*)carve((size_t)BB * K4W * 8);
    unsigned long long* wp4 = (unsigned long long*)carve((size_t)NOUT * K4W * 8);
    unsigned int* w2p       = (unsigned int*)carve((size_t)C2 * 9 * 4);
    double* sums            = (double*)carve((size_t)(32 + 32 + 64 + 64 + 2048 + 2048) * 8);
    double* sum1d = sums;        // 32
    double* var1d = sums + 32;   // 32
    double* sum2d = sums + 64;   // 64
    double* var2d = sums + 128;  // 64
    double* sum3d = sums + 192;  // 2048
    double* var3d = sums + 2240; // 2048
    float* fstats           = (float*)carve((size_t)(32 + 32 + 64 + 64 + 2048 + 2048) * 4);
    float* mean1 = fstats;          float* scale1 = fstats + 32;
    float* mean2 = fstats + 64;     float* scale2 = fstats + 128;
    float* mean3 = fstats + 192;    float* scale3 = fstats + 2240;

    hipMemsetAsync(sums, 0, (size_t)(32 + 32 + 64 + 64 + 2048 + 2048) * 8, stream);

    // layer 1
    conv1_stats<<<BB, 256, 0, stream>>>(x, w1, cb1, mean1, sum1d, 0);
    finalize_mean<<<1, 64, 0, stream>>>(sum1d, mean1, 32, (double)BB * IMG);
    conv1_stats<<<BB, 256, 0, stream>>>(x, w1, cb1, mean1, var1d, 1);
    finalize_scale<<<1, 64, 0, stream>>>(var1d, g1, scale1, 32, (double)BB * IMG);
    conv1_pack<<<BB, 256, 0, stream>>>(x, w1, cb1, mean1, scale1, bt1, s1p);

    // layer 2
    pack_w2<<<1, 576, 0, stream>>>(w2, w2p);
    conv2pool<<<BB, 256, 0, stream>>>(s1p, w2p, p2i);
    p2_stats<<<BB, 256, 0, stream>>>(p2i, cb2, mean2, sum2d, 0);
    finalize_mean<<<1, 64, 0, stream>>>(sum2d, mean2, 64, (double)BB * PP);
    p2_stats<<<BB, 256, 0, stream>>>(p2i, cb2, mean2, var2d, 1);
    finalize_scale<<<1, 64, 0, stream>>>(var2d, g2, scale2, 64, (double)BB * PP);
    p2_pack<<<(BB * K3W) / 4, 256, 0, stream>>>(p2i, cb2, mean2, scale2, bt2, hp3);

    // lin3
    w3_pack<<<(N3 * K3W) / 4, 256, 0, stream>>>(w3, wp3);
    lin3_gemm<<<dim3(32, 32), 256, 0, stream>>>(hp3, wp3, b3l, h3);
    h3_stats<<<dim3(8, 16), 256, 0, stream>>>(h3, mean3, sum3d, 0);
    finalize_mean<<<8, 256, 0, stream>>>(sum3d, mean3, 2048, (double)BB);
    h3_stats<<<dim3(8, 16), 256, 0, stream>>>(h3, mean3, var3d, 1);
    finalize_scale<<<8, 256, 0, stream>>>(var3d, g3, scale3, 2048, (double)BB);
    h3_pack<<<(BB * K4W) / 4, 256, 0, stream>>>(h3, mean3, scale3, bt3, h4p);

    // lin4
    w4_pack<<<(NOUT * K4W + 3) / 4, 256, 0, stream>>>(w4, wp4);
    lin4_out<<<(BB * NOUT) / 4, 256, 0, stream>>>(h4p, wp4, b4l, out);

    (void)in_sizes; (void)n_in; (void)out_size; (void)ws_size;
}

// Round 2
// 963.055 us; speedup vs baseline: 1.6456x; 1.6456x over previous
//
#include <hip/hip_runtime.h>

#define BB 2048
#define IMG 784
#define HWD 28
#define C1 32
#define C2 64
#define PP 169
#define PD 13
#define F3 10816
#define N3 2048
#define K3W 169
#define K4W 32
#define NOUT 10

__device__ __forceinline__ float ap2mag(float c) {
    // 2^round(log2(max(|c|,1e-38)))  (round half to even, like jnp.round)
    float a = fmaxf(fabsf(c), 1e-38f);
    return exp2f(rintf(log2f(a)));
}

// ---------------- conv1 (fp32 x, binarized weights) ----------------
// Thread layout: ch = tid&31, slice = tid>>5; 9 weights hoisted to named registers
// (NO private arrays -> no scratch spill; spill was the R1 700us pathology in conv1_pack).
// pass 0: per-channel sum of relu(conv+b); pass 1: per-channel sum of |c|*ap2(c)
__global__ void conv1_stats(const float* __restrict__ x, const float* __restrict__ w1,
                            const float* __restrict__ cb1, const float* __restrict__ meanIn,
                            double* __restrict__ outSum, int pass) {
    __shared__ float xs[IMG];
    __shared__ float ws[C1 * 9];
    __shared__ float red[256];
    int n = blockIdx.x, tid = threadIdx.x;
    for (int i = tid; i < IMG; i += 256) xs[i] = x[n * IMG + i];
    for (int i = tid; i < C1 * 9; i += 256) ws[i] = (w1[i] >= 0.f) ? 1.f : -1.f;
    __syncthreads();
    int ch = tid & 31, slice = tid >> 5;
    float b = cb1[ch];
    float m = pass ? meanIn[ch] : 0.f;
    float k0 = ws[ch * 9 + 0], k1 = ws[ch * 9 + 1], k2 = ws[ch * 9 + 2];
    float k3 = ws[ch * 9 + 3], k4 = ws[ch * 9 + 4], k5 = ws[ch * 9 + 5];
    float k6 = ws[ch * 9 + 6], k7 = ws[ch * 9 + 7], k8 = ws[ch * 9 + 8];
    float acc = 0.f;
    for (int p = slice; p < IMG; p += 8) {
        int py = p / HWD, px = p - py * HWD;
        bool tp = py > 0, bo = py < HWD - 1, lf = px > 0, rt = px < HWD - 1;
        const float* c0 = &xs[p];
        float s = c0[0] * k4;
        if (tp) {
            s += c0[-HWD] * k1;
            if (lf) s += c0[-HWD - 1] * k0;
            if (rt) s += c0[-HWD + 1] * k2;
        }
        if (lf) s += c0[-1] * k3;
        if (rt) s += c0[1] * k5;
        if (bo) {
            s += c0[HWD] * k7;
            if (lf) s += c0[HWD - 1] * k6;
            if (rt) s += c0[HWD + 1] * k8;
        }
        float v = fmaxf(s + b, 0.f);
        if (pass == 0) acc += v;
        else { float c = v - m; acc += fabsf(c) * ap2mag(c); }
    }
    red[tid] = acc;
    __syncthreads();
    if (tid < C1) {
        float t = 0.f;
        for (int sl = 0; sl < 8; sl++) t += red[sl * 32 + tid];
        atomicAdd(&outSum[tid], (double)t);
    }
}

// binarize(shift_bn(relu(conv1))) -> 32 channel bits packed per pixel.
// One thread per (channel, pixel-slice); __ballot packs 32 channel-signs:
// lanes 0-31 = pixel p_lo (low 32 bits), lanes 32-63 = pixel p_hi. 784 = 8*98
// so every thread runs exactly 98 iterations -> ballot is wave-uniform.
__global__ void conv1_pack(const float* __restrict__ x, const float* __restrict__ w1,
                           const float* __restrict__ cb1, const float* __restrict__ mean1,
                           const float* __restrict__ scale1, const float* __restrict__ beta1,
                           unsigned int* __restrict__ s1p) {
    __shared__ float xs[IMG];
    __shared__ float ws[C1 * 9];
    __shared__ unsigned int pbits[IMG];
    int n = blockIdx.x, tid = threadIdx.x;
    for (int i = tid; i < IMG; i += 256) xs[i] = x[n * IMG + i];
    for (int i = tid; i < C1 * 9; i += 256) ws[i] = (w1[i] >= 0.f) ? 1.f : -1.f;
    __syncthreads();
    int ch = tid & 31, slice = tid >> 5;
    float b = cb1[ch];
    float m = mean1[ch];
    float sc = scale1[ch];
    float bt = beta1[ch];
    float k0 = ws[ch * 9 + 0], k1 = ws[ch * 9 + 1], k2 = ws[ch * 9 + 2];
    float k3 = ws[ch * 9 + 3], k4 = ws[ch * 9 + 4], k5 = ws[ch * 9 + 5];
    float k6 = ws[ch * 9 + 6], k7 = ws[ch * 9 + 7], k8 = ws[ch * 9 + 8];
    int half = tid & 63;  // 0 or 32 writes
    for (int p = slice; p < IMG; p += 8) {
        int py = p / HWD, px = p - py * HWD;
        bool tp = py > 0, bo = py < HWD - 1, lf = px > 0, rt = px < HWD - 1;
        const float* c0 = &xs[p];
        float s = c0[0] * k4;
        if (tp) {
            s += c0[-HWD] * k1;
            if (lf) s += c0[-HWD - 1] * k0;
            if (rt) s += c0[-HWD + 1] * k2;
        }
        if (lf) s += c0[-1] * k3;
        if (rt) s += c0[1] * k5;
        if (bo) {
            s += c0[HWD] * k7;
            if (lf) s += c0[HWD - 1] * k6;
            if (rt) s += c0[HWD + 1] * k8;
        }
        float v = fmaxf(s + b, 0.f);
        float val = sc * (v - m) + bt;
        unsigned long long mask = __ballot(val >= 0.f);
        if (half == 0) pbits[p] = (unsigned int)mask;
        else if (half == 32) pbits[p] = (unsigned int)(mask >> 32);
    }
    __syncthreads();
    for (int i = tid; i < IMG; i += 256) s1p[n * IMG + i] = pbits[i];
}

// ---------------- conv2 weight packing ----------------
__global__ void pack_w2(const float* __restrict__ w2, unsigned int* __restrict__ w2p) {
    int t = blockIdx.x * blockDim.x + threadIdx.x;
    if (t >= C2 * 9) return;
    int oc = t / 9, k = t % 9;
    unsigned int bits = 0;
    for (int ic = 0; ic < C1; ic++)
        bits |= (w2[oc * 288 + ic * 9 + k] >= 0.f ? 1u : 0u) << ic;
    w2p[t] = bits;
}

// ---------------- fused conv2 + maxpool3s2 (pre-bias, pre-relu int) ----------------
__global__ void conv2pool(const unsigned int* __restrict__ s1p, const unsigned int* __restrict__ w2p,
                          short* __restrict__ p2i) {
    __shared__ unsigned int ss[IMG];
    __shared__ unsigned int wp[C2 * 9];
    int n = blockIdx.x, tid = threadIdx.x;
    for (int i = tid; i < IMG; i += 256) ss[i] = s1p[n * IMG + i];
    for (int i = tid; i < C2 * 9; i += 256) wp[i] = w2p[i];
    __syncthreads();
    for (int idx = tid; idx < C2 * PP; idx += 256) {
        int oc = idx / PP, pix = idx % PP;
        int py = pix / PD, px = pix % PD;
        int best = -1000000;
#pragma unroll
        for (int wy = 0; wy < 3; wy++) {
#pragma unroll
            for (int wx = 0; wx < 3; wx++) {
                int y = 2 * py + wy, xx0 = 2 * px + wx;
                int s = 0, cnt = 0;
#pragma unroll
                for (int ky = 0; ky < 3; ky++) {
                    int yy = y + ky - 1;
                    if (yy < 0 || yy >= HWD) continue;
#pragma unroll
                    for (int kx = 0; kx < 3; kx++) {
                        int xx = xx0 + kx - 1;
                        if (xx < 0 || xx >= HWD) continue;
                        s += __popc(ss[yy * HWD + xx] ^ wp[oc * 9 + ky * 3 + kx]);
                        cnt += 32;
                    }
                }
                int conv = cnt - 2 * s;
                best = max(best, conv);
            }
        }
        p2i[n * (C2 * PP) + idx] = (short)best;
    }
}

// ---------------- stats over pooled layer-2 ----------------
__global__ void p2_stats(const short* __restrict__ p2i, const float* __restrict__ cb2,
                         const float* __restrict__ meanIn, double* __restrict__ outSum, int pass) {
    __shared__ float red[256];
    int n = blockIdx.x, tid = threadIdx.x;
    int ch = tid & 63, slice = tid >> 6;
    float b = cb2[ch];
    float m = pass ? meanIn[ch] : 0.f;
    float acc = 0.f;
    const short* row = p2i + n * F3 + ch * PP;
    for (int p = slice; p < PP; p += 4) {
        float v = fmaxf((float)row[p] + b, 0.f);
        if (pass == 0) acc += v;
        else { float c = v - m; acc += fabsf(c) * ap2mag(c); }
    }
    red[tid] = acc;
    __syncthreads();
    if (tid < C2) {
        float t = 0.f;
        for (int sl = 0; sl < 4; sl++) t += red[sl * 64 + tid];
        atomicAdd(&outSum[tid], (double)t);
    }
}

// binarize layer-2 -> packed u64 rows (169 words per sample)
__global__ void p2_pack(const short* __restrict__ p2i, const float* __restrict__ cb2,
                        const float* __restrict__ mean2, const float* __restrict__ scale2,
                        const float* __restrict__ beta2, unsigned long long* __restrict__ hp3) {
    int gw = (blockIdx.x * blockDim.x + threadIdx.x) >> 6;
    int lane = threadIdx.x & 63;
    if (gw >= BB * K3W) return;
    int n = gw / K3W, j = gw % K3W;
    int f = j * 64 + lane;
    int oc = f / PP;
    float v = fmaxf((float)p2i[n * F3 + f] + cb2[oc], 0.f);
    float val = scale2[oc] * (v - mean2[oc]) + beta2[oc];
    unsigned long long mask = __ballot(val >= 0.f);
    if (lane == 0) hp3[n * K3W + j] = mask;
}

__global__ void w3_pack(const float* __restrict__ w3, unsigned long long* __restrict__ wp3) {
    int gw = (blockIdx.x * blockDim.x + threadIdx.x) >> 6;
    int lane = threadIdx.x & 63;
    if (gw >= N3 * K3W) return;
    int nn = gw / K3W, j = gw % K3W;
    float w = w3[(size_t)nn * F3 + j * 64 + lane];
    unsigned long long mask = __ballot(w >= 0.f);
    if (lane == 0) wp3[nn * K3W + j] = mask;
}

// ---------------- lin3: XNOR-popcount GEMM, 64x64 tile, 4x4 per thread ----------------
__global__ __launch_bounds__(256) void lin3_gemm(const unsigned long long* __restrict__ hp3,
                                                 const unsigned long long* __restrict__ wp3,
                                                 const float* __restrict__ b3l,
                                                 float* __restrict__ h3) {
    __shared__ unsigned long long aT[64][9];
    __shared__ unsigned long long bT[64][9];
    int tx = threadIdx.x & 15, ty = threadIdx.x >> 4;
    int m0 = blockIdx.y * 64, n0 = blockIdx.x * 64;
    int s[4][4];
#pragma unroll
    for (int i = 0; i < 4; i++)
#pragma unroll
        for (int j = 0; j < 4; j++) s[i][j] = 0;
    for (int k0 = 0; k0 < K3W; k0 += 8) {
        for (int t = threadIdx.x; t < 512; t += 256) {
            int r = t >> 3, kk = t & 7;
            int k = k0 + kk;
            aT[r][kk] = (k < K3W) ? hp3[(m0 + r) * K3W + k] : 0ULL;
            bT[r][kk] = (k < K3W) ? wp3[(n0 + r) * K3W + k] : 0ULL;
        }
        __syncthreads();
#pragma unroll
        for (int kk = 0; kk < 8; kk++) {
            unsigned long long a[4], b[4];
#pragma unroll
            for (int i = 0; i < 4; i++) a[i] = aT[ty * 4 + i][kk];
#pragma unroll
            for (int j = 0; j < 4; j++) b[j] = bT[tx * 4 + j][kk];
#pragma unroll
            for (int i = 0; i < 4; i++)
#pragma unroll
                for (int j = 0; j < 4; j++) s[i][j] += __popcll(a[i] ^ b[j]);
        }
        __syncthreads();
    }
#pragma unroll
    for (int i = 0; i < 4; i++) {
        int m = m0 + ty * 4 + i;
#pragma unroll
        for (int j = 0; j < 4; j++) {
            int nn = n0 + tx * 4 + j;
            float v = fmaxf((float)(F3 - 2 * s[i][j]) + b3l[nn], 0.f);
            h3[(size_t)m * N3 + nn] = v;
        }
    }
}

// ---------------- stats over h3 (per feature, across batch) ----------------
__global__ void h3_stats(const float* __restrict__ h3, const float* __restrict__ meanIn,
                         double* __restrict__ outSum, int pass) {
    int nn = blockIdx.x * 256 + threadIdx.x;
    int m0 = blockIdx.y * 128;
    float m = pass ? meanIn[nn] : 0.f;
    float acc = 0.f;
    for (int mm = m0; mm < m0 + 128; mm++) {
        float v = h3[(size_t)mm * N3 + nn];
        if (pass == 0) acc += v;
        else { float c = v - m; acc += fabsf(c) * ap2mag(c); }
    }
    atomicAdd(&outSum[nn], (double)acc);
}

__global__ void h3_pack(const float* __restrict__ h3, const float* __restrict__ mean3,
                        const float* __restrict__ scale3, const float* __restrict__ beta3,
                        unsigned long long* __restrict__ h4p) {
    int gw = (blockIdx.x * blockDim.x + threadIdx.x) >> 6;
    int lane = threadIdx.x & 63;
    if (gw >= BB * K4W) return;
    int m = gw / K4W, j = gw % K4W;
    int f = j * 64 + lane;
    float v = h3[(size_t)m * N3 + f];
    float val = scale3[f] * (v - mean3[f]) + beta3[f];
    unsigned long long mask = __ballot(val >= 0.f);
    if (lane == 0) h4p[m * K4W + j] = mask;
}

__global__ void w4_pack(const float* __restrict__ w4, unsigned long long* __restrict__ wp4) {
    int gw = (blockIdx.x * blockDim.x + threadIdx.x) >> 6;
    int lane = threadIdx.x & 63;
    if (gw >= NOUT * K4W) return;
    int o = gw / K4W, j = gw % K4W;
    float w = w4[o * N3 + j * 64 + lane];
    unsigned long long mask = __ballot(w >= 0.f);
    if (lane == 0) wp4[o * K4W + j] = mask;
}

__global__ void lin4_out(const unsigned long long* __restrict__ h4p,
                         const unsigned long long* __restrict__ wp4,
                         const float* __restrict__ b4, float* __restrict__ out) {
    int gw = (blockIdx.x * blockDim.x + threadIdx.x) >> 6;
    int lane = threadIdx.x & 63;
    if (gw >= BB * NOUT) return;
    int m = gw / NOUT, o = gw % NOUT;
    int c = 0;
    if (lane < K4W) c = __popcll(h4p[m * K4W + lane] ^ wp4[o * K4W + lane]);
    for (int off = 32; off; off >>= 1) c += __shfl_down(c, off);
    if (lane == 0) out[m * NOUT + o] = (float)(N3 - 2 * c) + b4[o];
}

// ---------------- small finalize kernels ----------------
__global__ void finalize_mean(const double* __restrict__ sumd, float* __restrict__ meanOut,
                              int n, double count) {
    int i = blockIdx.x * blockDim.x + threadIdx.x;
    if (i < n) meanOut[i] = (float)(sumd[i] / count);
}

__global__ void finalize_scale(const double* __restrict__ vard, const float* __restrict__ g,
                               float* __restrict__ scaleOut, int n, double count) {
    int i = blockIdx.x * blockDim.x + threadIdx.x;
    if (i >= n) return;
    float var = (float)(vard[i] / count);
    float t = var + 1e-4f;
    float inv = 1.0f / sqrtf(t);
    double p = exp2(rint(log2((double)inv)));
    float gg = g[i];
    float ap2g;
    if (gg == 0.f) ap2g = 0.f;
    else {
        double ag = fabs((double)gg);
        if (ag < 1e-38) ag = 1e-38;
        ap2g = (float)exp2(rint(log2(ag)));
        if (gg < 0.f) ap2g = -ap2g;
    }
    scaleOut[i] = ap2g * (float)p;
}

extern "C" void kernel_launch(void* const* d_in, const int* in_sizes, int n_in,
                              void* d_out, int out_size, void* d_ws, size_t ws_size,
                              hipStream_t stream) {
    const float* x   = (const float*)d_in[0];
    const float* w1  = (const float*)d_in[1];
    const float* cb1 = (const float*)d_in[2];
    const float* g1  = (const float*)d_in[3];
    const float* bt1 = (const float*)d_in[4];
    const float* w2  = (const float*)d_in[5];
    const float* cb2 = (const float*)d_in[6];
    const float* g2  = (const float*)d_in[7];
    const float* bt2 = (const float*)d_in[8];
    const float* w3  = (const float*)d_in[9];
    const float* b3l = (const float*)d_in[10];
    const float* g3  = (const float*)d_in[11];
    const float* bt3 = (const float*)d_in[12];
    const float* w4  = (const float*)d_in[13];
    const float* b4l = (const float*)d_in[14];
    float* out = (float*)d_out;

    char* base = (char*)d_ws;
    size_t off = 0;
    auto carve = [&](size_t bytes) { char* p = base + off; off = (off + bytes + 255) & ~(size_t)255; return p; };
    unsigned int* s1p       = (unsigned int*)carve((size_t)BB * IMG * 4);
    short* p2i              = (short*)carve((size_t)BB * C2 * PP * 2);
    unsigned long long* hp3 = (unsigned long long*)carve((size_t)BB * K3W * 8);
    unsigned long long* wp3 = (unsigned long long*)carve((size_t)N3 * K3W * 8);
    float* h3               = (float*)carve((size_t)BB * N3 * 4);
    unsigned long long* h4p = (unsigned long long*)carve((size_t)BB * K4W * 8);
    unsigned long long* wp4 = (unsigned long long*)carve((size_t)NOUT * K4W * 8);
    unsigned int* w2p       = (unsigned int*)carve((size_t)C2 * 9 * 4);
    double* sums            = (double*)carve((size_t)(32 + 32 + 64 + 64 + 2048 + 2048) * 8);
    double* sum1d = sums;        // 32
    double* var1d = sums + 32;   // 32
    double* sum2d = sums + 64;   // 64
    double* var2d = sums + 128;  // 64
    double* sum3d = sums + 192;  // 2048
    double* var3d = sums + 2240; // 2048
    float* fstats           = (float*)carve((size_t)(32 + 32 + 64 + 64 + 2048 + 2048) * 4);
    float* mean1 = fstats;          float* scale1 = fstats + 32;
    float* mean2 = fstats + 64;     float* scale2 = fstats + 128;
    float* mean3 = fstats + 192;    float* scale3 = fstats + 2240;

    hipMemsetAsync(sums, 0, (size_t)(32 + 32 + 64 + 64 + 2048 + 2048) * 8, stream);

    // layer 1
    conv1_stats<<<BB, 256, 0, stream>>>(x, w1, cb1, mean1, sum1d, 0);
    finalize_mean<<<1, 64, 0, stream>>>(sum1d, mean1, 32, (double)BB * IMG);
    conv1_stats<<<BB, 256, 0, stream>>>(x, w1, cb1, mean1, var1d, 1);
    finalize_scale<<<1, 64, 0, stream>>>(var1d, g1, scale1, 32, (double)BB * IMG);
    conv1_pack<<<BB, 256, 0, stream>>>(x, w1, cb1, mean1, scale1, bt1, s1p);

    // layer 2
    pack_w2<<<1, 576, 0, stream>>>(w2, w2p);
    conv2pool<<<BB, 256, 0, stream>>>(s1p, w2p, p2i);
    p2_stats<<<BB, 256, 0, stream>>>(p2i, cb2, mean2, sum2d, 0);
    finalize_mean<<<1, 64, 0, stream>>>(sum2d, mean2, 64, (double)BB * PP);
    p2_stats<<<BB, 256, 0, stream>>>(p2i, cb2, mean2, var2d, 1);
    finalize_scale<<<1, 64, 0, stream>>>(var2d, g2, scale2, 64, (double)BB * PP);
    p2_pack<<<(BB * K3W) / 4, 256, 0, stream>>>(p2i, cb2, mean2, scale2, bt2, hp3);

    // lin3
    w3_pack<<<(N3 * K3W) / 4, 256, 0, stream>>>(w3, wp3);
    lin3_gemm<<<dim3(32, 32), 256, 0, stream>>>(hp3, wp3, b3l, h3);
    h3_stats<<<dim3(8, 16), 256, 0, stream>>>(h3, mean3, sum3d, 0);
    finalize_mean<<<8, 256, 0, stream>>>(sum3d, mean3, 2048, (double)BB);
    h3_stats<<<dim3(8, 16), 256, 0, stream>>>(h3, mean3, var3d, 1);
    finalize_scale<<<8, 256, 0, stream>>>(var3d, g3, scale3, 2048, (double)BB);
    h3_pack<<<(BB * K4W) / 4, 256, 0, stream>>>(h3, mean3, scale3, bt3, h4p);

    // lin4
    w4_pack<<<(NOUT * K4W + 3) / 4, 256, 0, stream>>>(w4, wp4);
    lin4_out<<<(BB * NOUT) / 4, 256, 0, stream>>>(h4p, wp4, b4l, out);

    (void)in_sizes; (void)n_in; (void)out_size; (void)ws_size;
}